// Round 3
// baseline (498.982 us; speedup 1.0000x reference)
//
#include <hip/hip_runtime.h>

typedef __bf16 bf16;
typedef __bf16 bf16x4 __attribute__((ext_vector_type(4)));
typedef __bf16 bf16x8 __attribute__((ext_vector_type(8)));
typedef float f32x4 __attribute__((ext_vector_type(4)));

#define S_LEN 2048
#define HIDDEN 2048
#define NH 16
#define NKV 8
#define HD 128
#define QKV_N 4096

__device__ __forceinline__ void async_load16(const void* g, void* l) {
  __builtin_amdgcn_global_load_lds((const __attribute__((address_space(1))) unsigned int*)g,
                                   (__attribute__((address_space(3))) unsigned int*)l,
                                   16, 0, 0);
}

// ---------------- fp32 -> bf16 convert ----------------
__global__ __launch_bounds__(256)
void cvt_f32_bf16(const float* __restrict__ src, bf16* __restrict__ dst, int n) {
  int i = (blockIdx.x * 256 + threadIdx.x) * 4;
  if (i < n) {
    float4 v = *(const float4*)(src + i);
    bf16x4 o = {(bf16)v.x, (bf16)v.y, (bf16)v.z, (bf16)v.w};
    *(bf16x4*)(dst + i) = o;
  }
}

// ---------------- GEMM 128x128: C[M,N] = A[M,K] * B[N,K]^T + bias ----------------
template <int WRITE_BF16>
__global__ __launch_bounds__(256)
void gemm_bt(const bf16* __restrict__ A, const bf16* __restrict__ B,
             const float* __restrict__ bias, void* __restrict__ Cout,
             int M, int N, int K) {
  __shared__ bf16 As[128 * 32];
  __shared__ bf16 Bs[128 * 32];
  const int tid = threadIdx.x;
  const int w = tid >> 6, lane = tid & 63;
  const int quad = lane >> 4, l15 = lane & 15;
  const int wm = w >> 1, wn = w & 1;
  const int m0 = blockIdx.y * 128, n0 = blockIdx.x * 128;

  f32x4 acc[4][4];
#pragma unroll
  for (int i = 0; i < 4; i++)
#pragma unroll
    for (int j = 0; j < 4; j++) acc[i][j] = (f32x4){0.f, 0.f, 0.f, 0.f};

  const int crow = lane >> 2;
  const int ccol = (lane & 3) * 8;

  for (int k0 = 0; k0 < K; k0 += 32) {
    __syncthreads();
#pragma unroll
    for (int q = 0; q < 2; q++) {
      int c = 2 * w + q;
      async_load16(A + (size_t)(m0 + c * 16 + crow) * K + k0 + ccol, (char*)As + c * 1024);
      async_load16(B + (size_t)(n0 + c * 16 + crow) * K + k0 + ccol, (char*)Bs + c * 1024);
    }
    __syncthreads();
    bf16x8 af[4], bfr[4];
#pragma unroll
    for (int i = 0; i < 4; i++)
      af[i] = *(const bf16x8*)(As + (wm * 64 + i * 16 + l15) * 32 + quad * 8);
#pragma unroll
    for (int j = 0; j < 4; j++)
      bfr[j] = *(const bf16x8*)(Bs + (wn * 64 + j * 16 + l15) * 32 + quad * 8);
#pragma unroll
    for (int i = 0; i < 4; i++)
#pragma unroll
      for (int j = 0; j < 4; j++)
        acc[i][j] = __builtin_amdgcn_mfma_f32_16x16x32_bf16(af[i], bfr[j], acc[i][j], 0, 0, 0);
  }

#pragma unroll
  for (int i = 0; i < 4; i++) {
#pragma unroll
    for (int j = 0; j < 4; j++) {
      int col = n0 + wn * 64 + j * 16 + l15;
      float bv = bias[col];
#pragma unroll
      for (int r = 0; r < 4; r++) {
        int row = m0 + wm * 64 + i * 16 + quad * 4 + r;
        float v = acc[i][j][r] + bv;
        if (WRITE_BF16)
          ((bf16*)Cout)[(size_t)row * N + col] = (bf16)v;
        else
          ((float*)Cout)[(size_t)row * N + col] = v;
      }
    }
  }
}

// ---------------- GEMM 128x64 (more blocks for square shapes), fp32 out ----------------
__global__ __launch_bounds__(256)
void gemm_bt64(const bf16* __restrict__ A, const bf16* __restrict__ B,
               const float* __restrict__ bias, float* __restrict__ Cout,
               int M, int N, int K) {
  __shared__ bf16 As[128 * 32];  // 8 chunks
  __shared__ bf16 Bs[64 * 32];   // 4 chunks
  const int tid = threadIdx.x;
  const int w = tid >> 6, lane = tid & 63;
  const int quad = lane >> 4, l15 = lane & 15;
  const int m0 = blockIdx.y * 128, n0 = blockIdx.x * 64;

  f32x4 acc[2][4];
#pragma unroll
  for (int i = 0; i < 2; i++)
#pragma unroll
    for (int j = 0; j < 4; j++) acc[i][j] = (f32x4){0.f, 0.f, 0.f, 0.f};

  const int crow = lane >> 2;
  const int ccol = (lane & 3) * 8;

  for (int k0 = 0; k0 < K; k0 += 32) {
    __syncthreads();
#pragma unroll
    for (int q = 0; q < 2; q++) {
      int c = 2 * w + q;
      async_load16(A + (size_t)(m0 + c * 16 + crow) * K + k0 + ccol, (char*)As + c * 1024);
    }
    async_load16(B + (size_t)(n0 + w * 16 + crow) * K + k0 + ccol, (char*)Bs + w * 1024);
    __syncthreads();
    bf16x8 af[2], bfr[4];
#pragma unroll
    for (int i = 0; i < 2; i++)
      af[i] = *(const bf16x8*)(As + (w * 32 + i * 16 + l15) * 32 + quad * 8);
#pragma unroll
    for (int j = 0; j < 4; j++)
      bfr[j] = *(const bf16x8*)(Bs + (j * 16 + l15) * 32 + quad * 8);
#pragma unroll
    for (int i = 0; i < 2; i++)
#pragma unroll
      for (int j = 0; j < 4; j++)
        acc[i][j] = __builtin_amdgcn_mfma_f32_16x16x32_bf16(af[i], bfr[j], acc[i][j], 0, 0, 0);
  }

#pragma unroll
  for (int i = 0; i < 2; i++) {
#pragma unroll
    for (int j = 0; j < 4; j++) {
      int col = n0 + j * 16 + l15;
      float bv = bias[col];
#pragma unroll
      for (int r = 0; r < 4; r++) {
        int row = m0 + w * 32 + i * 16 + quad * 4 + r;
        Cout[(size_t)row * N + col] = acc[i][j][r] + bv;
      }
    }
  }
}

// ---------------- RMS norm + RoPE -> Q/K head-major bf16 ----------------
// grid (S, 24): y<16 -> Q head y ; 16<=y<24 -> K head y-16.
__global__ __launch_bounds__(128)
void normrope(const bf16* __restrict__ qkv, const int* __restrict__ idx,
              const float* __restrict__ qnw, const float* __restrict__ knw,
              const float* __restrict__ qnhw, const float* __restrict__ knhw,
              bf16* __restrict__ Qb, bf16* __restrict__ Kb) {
  const int s = blockIdx.x;
  const int y = blockIdx.y;
  const int d = threadIdx.x;

  const bool isq = (y < 16);
  const int off = isq ? (y * HD + d) : (2048 + (y - 16) * HD + d);
  float x = (float)qkv[(size_t)s * QKV_N + off];

  float ss = x * x;
#pragma unroll
  for (int o = 32; o; o >>= 1) ss += __shfl_xor(ss, o);
  float inv = rsqrtf(ss * (1.f / 64.f) + 1e-6f);
  const float* wt = (d < 64) ? (isq ? qnw : knw) : (isq ? qnhw : knhw);
  float yn = x * inv * wt[d & 63];

  float pos, invf;
  int xorm;
  bool firsthalf;
  if (d < 64) {
    pos = (float)idx[s];
    int i = d & 31;
    invf = exp2f(-(float)i * 0.6228615177913804f);  // log2(1e6)/32
    xorm = 32;
    firsthalf = (d < 32);
  } else {
    int j = d - 64;
    int region = j >> 5;
    pos = (float)idx[(1 + region) * S_LEN + s];
    int i = j & 15;
    invf = exp2f(-(float)i * 0.8304820237218406f);  // log2(1e4)/16
    xorm = 16;
    firsthalf = ((j & 31) < 16);
  }
  float ang = pos * invf;
  float si, co;
  sincosf(ang, &si, &co);
  float partner = __shfl_xor(yn, xorm);
  float outv = firsthalf ? (yn * co - partner * si) : (yn * co + partner * si);

  if (isq)
    Qb[((size_t)y * S_LEN + s) * HD + d] = (bf16)outv;
  else
    Kb[((size_t)(y - 16) * S_LEN + s) * HD + d] = (bf16)outv;
}

// ---------------- V transpose: qkvB[s][3072+kv*128+d] -> VT[kv][d][s] ----------------
__global__ __launch_bounds__(256)
void vtrans(const bf16* __restrict__ qkv, bf16* __restrict__ VT) {
  __shared__ bf16 T[64][72];
  const int tid = threadIdx.x;
  const int s0 = blockIdx.x * 64, d0 = blockIdx.y * 64, kv = blockIdx.z;
#pragma unroll
  for (int it = 0; it < 2; it++) {
    int r = (tid >> 3) + it * 32;
    int c = (tid & 7) * 8;
    bf16x8 v = *(const bf16x8*)(qkv + (size_t)(s0 + r) * QKV_N + 3072 + kv * HD + d0 + c);
    *(bf16x8*)(&T[r][c]) = v;
  }
  __syncthreads();
#pragma unroll
  for (int it = 0; it < 2; it++) {
    int r = (tid >> 3) + it * 32;   // d row
    int c = (tid & 7) * 8;          // s col
    bf16x8 o;
#pragma unroll
    for (int j = 0; j < 8; j++) o[j] = T[c + j][r];
    *(bf16x8*)(VT + ((size_t)kv * HD + d0 + r) * S_LEN + s0 + c) = o;
  }
}

// ---------------- Flash attention: barrier-free, wave-autonomous ----------------
// 512 blocks x 256 thr. block b: head = b&15, strip-group sg = 31-(b>>4) (longest first).
// wave w handles strip = sg*4+w (16 Q rows); all 4 waves have exactly sg+1 T64 tiles.
// K fragments direct from global Kb[t][d]; V fragments direct from VT[d][t]. LDS: P only.
__global__ __launch_bounds__(256)
void attn_fused(const bf16* __restrict__ Qb, const bf16* __restrict__ Kb,
                const bf16* __restrict__ VT, bf16* __restrict__ attnO) {
  __shared__ __align__(16) bf16 Ps[4][16][72];
  const int tid = threadIdx.x;
  const int w = tid >> 6, lane = tid & 63;
  const int quad = lane >> 4, l15 = lane & 15;
  const int b = blockIdx.x;
  const int h = b & 15;
  const int sg = 31 - (b >> 4);
  const int strip = sg * 4 + w;
  const int qr0 = strip * 16;
  const int nT = sg + 1;
  const int kv = h >> 1;

  const bf16* Qg = Qb + (size_t)h * S_LEN * HD;
  const bf16* Kg = Kb + (size_t)kv * S_LEN * HD;
  const bf16* Vg = VT + (size_t)kv * HD * S_LEN;

  bf16x8 aq[4];
#pragma unroll
  for (int kc = 0; kc < 4; kc++)
    aq[kc] = *(const bf16x8*)(Qg + (size_t)(qr0 + l15) * HD + kc * 32 + quad * 8);

  float m2[4], li[4];
  f32x4 Oacc[8];
#pragma unroll
  for (int r = 0; r < 4; r++) { m2[r] = -1e30f; li[r] = 0.f; }
#pragma unroll
  for (int dt = 0; dt < 8; dt++) Oacc[dt] = (f32x4){0.f, 0.f, 0.f, 0.f};

  const float SC2 = 0.12751745f;  // D^-0.5 * log2(e)

  for (int tt = 0; tt < nT; ++tt) {
    const int t0 = tt << 6;
    const bool full = (t0 + 64 <= qr0);  // wave-uniform

    // ---- QK^T over 64 T cols ----
    f32x4 sacc[4];
#pragma unroll
    for (int nt = 0; nt < 4; nt++) {
      sacc[nt] = (f32x4){0.f, 0.f, 0.f, 0.f};
#pragma unroll
      for (int kc = 0; kc < 4; kc++) {
        bf16x8 bk = *(const bf16x8*)(Kg + (size_t)(t0 + nt * 16 + l15) * HD + kc * 32 + quad * 8);
        sacc[nt] = __builtin_amdgcn_mfma_f32_16x16x32_bf16(aq[kc], bk, sacc[nt], 0, 0, 0);
      }
    }

    // ---- online softmax over 64 cols, base-2 ----
#pragma unroll
    for (int r = 0; r < 4; r++) {
      const int mrow = qr0 + quad * 4 + r;
      float s0 = sacc[0][r] * SC2, s1 = sacc[1][r] * SC2;
      float s2 = sacc[2][r] * SC2, s3 = sacc[3][r] * SC2;
      if (!full) {
        int cb = t0 + l15;
        if (cb > mrow) s0 = -1e30f;
        if (cb + 16 > mrow) s1 = -1e30f;
        if (cb + 32 > mrow) s2 = -1e30f;
        if (cb + 48 > mrow) s3 = -1e30f;
      }
      float mx = fmaxf(fmaxf(s0, s1), fmaxf(s2, s3));
#pragma unroll
      for (int o = 8; o; o >>= 1) mx = fmaxf(mx, __shfl_xor(mx, o));
      float mnew = fmaxf(m2[r], mx);
      float alpha = exp2f(m2[r] - mnew);
      float p0 = exp2f(s0 - mnew), p1 = exp2f(s1 - mnew);
      float p2 = exp2f(s2 - mnew), p3 = exp2f(s3 - mnew);
      float rs = (p0 + p1) + (p2 + p3);
#pragma unroll
      for (int o = 8; o; o >>= 1) rs += __shfl_xor(rs, o);
      li[r] = li[r] * alpha + rs;
      m2[r] = mnew;
#pragma unroll
      for (int dt = 0; dt < 8; dt++) Oacc[dt][r] *= alpha;
      Ps[w][quad * 4 + r][l15] = (bf16)p0;
      Ps[w][quad * 4 + r][16 + l15] = (bf16)p1;
      Ps[w][quad * 4 + r][32 + l15] = (bf16)p2;
      Ps[w][quad * 4 + r][48 + l15] = (bf16)p3;
    }
    __asm__ __volatile__("s_waitcnt lgkmcnt(0)" ::: "memory");  // wave-local P RAW

    // ---- PV ----
#pragma unroll
    for (int half = 0; half < 2; half++) {
      bf16x8 ap = *(const bf16x8*)(&Ps[w][l15][half * 32 + quad * 8]);
#pragma unroll
      for (int dt = 0; dt < 8; dt++) {
        bf16x8 bv = *(const bf16x8*)(Vg + (size_t)(dt * 16 + l15) * S_LEN + t0 + half * 32 + quad * 8);
        Oacc[dt] = __builtin_amdgcn_mfma_f32_16x16x32_bf16(ap, bv, Oacc[dt], 0, 0, 0);
      }
    }
  }

#pragma unroll
  for (int r = 0; r < 4; r++) {
    float invl = 1.f / li[r];
    int srow = qr0 + quad * 4 + r;
#pragma unroll
    for (int dt = 0; dt < 8; dt++)
      attnO[(size_t)srow * HIDDEN + h * HD + dt * 16 + l15] = (bf16)(Oacc[dt][r] * invl);
  }
}

extern "C" void kernel_launch(void* const* d_in, const int* in_sizes, int n_in,
                              void* d_out, int out_size, void* d_ws, size_t ws_size,
                              hipStream_t stream) {
  const float* hidden = (const float*)d_in[0];
  const int* idx = (const int*)d_in[1];
  const float* qkv_w = (const float*)d_in[3];
  const float* qkv_b = (const float*)d_in[4];
  const float* o_w = (const float*)d_in[5];
  const float* o_b = (const float*)d_in[6];
  const float* qnw = (const float*)d_in[7];
  const float* knw = (const float*)d_in[8];
  const float* qnhw = (const float*)d_in[9];
  const float* knhw = (const float*)d_in[10];

  char* ws = (char*)d_ws;
  bf16* hB   = (bf16*)(ws);               // 8 MB
  bf16* qwB  = (bf16*)(ws + (8u << 20));  // 16 MB
  bf16* qkvB = (bf16*)(ws + (24u << 20)); // 16 MB
  bf16* Qb   = (bf16*)(ws + (40u << 20)); // 8 MB
  bf16* Kb   = (bf16*)(ws + (48u << 20)); // 4 MB
  bf16* VT   = (bf16*)(ws + (52u << 20)); // 4 MB
  bf16* owB  = hB;                        // reuse after GEMM1
  bf16* attn = qwB;                       // reuse after GEMM1

  cvt_f32_bf16<<<HIDDEN * S_LEN / 1024, 256, 0, stream>>>(hidden, hB, HIDDEN * S_LEN);
  cvt_f32_bf16<<<QKV_N * HIDDEN / 1024, 256, 0, stream>>>(qkv_w, qwB, QKV_N * HIDDEN);

  gemm_bt<1><<<dim3(QKV_N / 128, S_LEN / 128), 256, 0, stream>>>(
      hB, qwB, qkv_b, qkvB, S_LEN, QKV_N, HIDDEN);

  cvt_f32_bf16<<<HIDDEN * HIDDEN / 1024, 256, 0, stream>>>(o_w, owB, HIDDEN * HIDDEN);

  normrope<<<dim3(S_LEN, 24), 128, 0, stream>>>(qkvB, idx, qnw, knw, qnhw, knhw, Qb, Kb);
  vtrans<<<dim3(S_LEN / 64, HD / 64, NKV), 256, 0, stream>>>(qkvB, VT);

  attn_fused<<<512, 256, 0, stream>>>(Qb, Kb, VT, attn);

  gemm_bt64<<<dim3(HIDDEN / 64, S_LEN / 128), 256, 0, stream>>>(
      attn, owB, o_b, (float*)d_out, S_LEN, HIDDEN, HIDDEN);
}

// Round 4
// 312.051 us; speedup vs baseline: 1.5990x; 1.5990x over previous
//
#include <hip/hip_runtime.h>

typedef __bf16 bf16;
typedef __bf16 bf16x4 __attribute__((ext_vector_type(4)));
typedef __bf16 bf16x8 __attribute__((ext_vector_type(8)));
typedef float f32x4 __attribute__((ext_vector_type(4)));

#define S_LEN 2048
#define HIDDEN 2048
#define NH 16
#define NKV 8
#define HD 128
#define QKV_N 4096

__device__ __forceinline__ void async_load16(const void* g, void* l) {
  __builtin_amdgcn_global_load_lds((const __attribute__((address_space(1))) unsigned int*)g,
                                   (__attribute__((address_space(3))) unsigned int*)l,
                                   16, 0, 0);
}

// ---- DPP 16-lane (row) reductions: row == our quad domain (l15) ----
template <int C>
__device__ __forceinline__ float dpp_f(float x) {
  return __builtin_bit_cast(float, __builtin_amdgcn_mov_dpp(
      __builtin_bit_cast(int, x), C, 0xF, 0xF, true));
}
__device__ __forceinline__ float rowmax16(float x) {
  x = fmaxf(x, dpp_f<0x128>(x));  // row_ror:8
  x = fmaxf(x, dpp_f<0x124>(x));  // row_ror:4
  x = fmaxf(x, dpp_f<0x122>(x));  // row_ror:2
  x = fmaxf(x, dpp_f<0x121>(x));  // row_ror:1
  return x;
}
__device__ __forceinline__ float rowsum16(float x) {
  x += dpp_f<0x128>(x);
  x += dpp_f<0x124>(x);
  x += dpp_f<0x122>(x);
  x += dpp_f<0x121>(x);
  return x;
}

// ---------------- fp32 -> bf16 convert ----------------
__global__ __launch_bounds__(256)
void cvt_f32_bf16(const float* __restrict__ src, bf16* __restrict__ dst, int n) {
  int i = (blockIdx.x * 256 + threadIdx.x) * 4;
  if (i < n) {
    float4 v = *(const float4*)(src + i);
    bf16x4 o = {(bf16)v.x, (bf16)v.y, (bf16)v.z, (bf16)v.w};
    *(bf16x4*)(dst + i) = o;
  }
}

// ---------------- GEMM 128x128: C[M,N] = A[M,K] * B[N,K]^T + bias ----------------
template <int WRITE_BF16>
__global__ __launch_bounds__(256)
void gemm_bt(const bf16* __restrict__ A, const bf16* __restrict__ B,
             const float* __restrict__ bias, void* __restrict__ Cout,
             int M, int N, int K) {
  __shared__ bf16 As[128 * 32];
  __shared__ bf16 Bs[128 * 32];
  const int tid = threadIdx.x;
  const int w = tid >> 6, lane = tid & 63;
  const int quad = lane >> 4, l15 = lane & 15;
  const int wm = w >> 1, wn = w & 1;
  const int m0 = blockIdx.y * 128, n0 = blockIdx.x * 128;

  f32x4 acc[4][4];
#pragma unroll
  for (int i = 0; i < 4; i++)
#pragma unroll
    for (int j = 0; j < 4; j++) acc[i][j] = (f32x4){0.f, 0.f, 0.f, 0.f};

  const int crow = lane >> 2;
  const int ccol = (lane & 3) * 8;

  for (int k0 = 0; k0 < K; k0 += 32) {
    __syncthreads();
#pragma unroll
    for (int q = 0; q < 2; q++) {
      int c = 2 * w + q;
      async_load16(A + (size_t)(m0 + c * 16 + crow) * K + k0 + ccol, (char*)As + c * 1024);
      async_load16(B + (size_t)(n0 + c * 16 + crow) * K + k0 + ccol, (char*)Bs + c * 1024);
    }
    __syncthreads();
    bf16x8 af[4], bfr[4];
#pragma unroll
    for (int i = 0; i < 4; i++)
      af[i] = *(const bf16x8*)(As + (wm * 64 + i * 16 + l15) * 32 + quad * 8);
#pragma unroll
    for (int j = 0; j < 4; j++)
      bfr[j] = *(const bf16x8*)(Bs + (wn * 64 + j * 16 + l15) * 32 + quad * 8);
#pragma unroll
    for (int i = 0; i < 4; i++)
#pragma unroll
      for (int j = 0; j < 4; j++)
        acc[i][j] = __builtin_amdgcn_mfma_f32_16x16x32_bf16(af[i], bfr[j], acc[i][j], 0, 0, 0);
  }

#pragma unroll
  for (int i = 0; i < 4; i++) {
#pragma unroll
    for (int j = 0; j < 4; j++) {
      int col = n0 + wn * 64 + j * 16 + l15;
      float bv = bias[col];
#pragma unroll
      for (int r = 0; r < 4; r++) {
        int row = m0 + wm * 64 + i * 16 + quad * 4 + r;
        float v = acc[i][j][r] + bv;
        if (WRITE_BF16)
          ((bf16*)Cout)[(size_t)row * N + col] = (bf16)v;
        else
          ((float*)Cout)[(size_t)row * N + col] = v;
      }
    }
  }
}

// ---------------- GEMM 128x64, fp32 out ----------------
__global__ __launch_bounds__(256)
void gemm_bt64(const bf16* __restrict__ A, const bf16* __restrict__ B,
               const float* __restrict__ bias, float* __restrict__ Cout,
               int M, int N, int K) {
  __shared__ bf16 As[128 * 32];
  __shared__ bf16 Bs[64 * 32];
  const int tid = threadIdx.x;
  const int w = tid >> 6, lane = tid & 63;
  const int quad = lane >> 4, l15 = lane & 15;
  const int m0 = blockIdx.y * 128, n0 = blockIdx.x * 64;

  f32x4 acc[2][4];
#pragma unroll
  for (int i = 0; i < 2; i++)
#pragma unroll
    for (int j = 0; j < 4; j++) acc[i][j] = (f32x4){0.f, 0.f, 0.f, 0.f};

  const int crow = lane >> 2;
  const int ccol = (lane & 3) * 8;

  for (int k0 = 0; k0 < K; k0 += 32) {
    __syncthreads();
#pragma unroll
    for (int q = 0; q < 2; q++) {
      int c = 2 * w + q;
      async_load16(A + (size_t)(m0 + c * 16 + crow) * K + k0 + ccol, (char*)As + c * 1024);
    }
    async_load16(B + (size_t)(n0 + w * 16 + crow) * K + k0 + ccol, (char*)Bs + w * 1024);
    __syncthreads();
    bf16x8 af[2], bfr[4];
#pragma unroll
    for (int i = 0; i < 2; i++)
      af[i] = *(const bf16x8*)(As + (w * 32 + i * 16 + l15) * 32 + quad * 8);
#pragma unroll
    for (int j = 0; j < 4; j++)
      bfr[j] = *(const bf16x8*)(Bs + (j * 16 + l15) * 32 + quad * 8);
#pragma unroll
    for (int i = 0; i < 2; i++)
#pragma unroll
      for (int j = 0; j < 4; j++)
        acc[i][j] = __builtin_amdgcn_mfma_f32_16x16x32_bf16(af[i], bfr[j], acc[i][j], 0, 0, 0);
  }

#pragma unroll
  for (int i = 0; i < 2; i++) {
#pragma unroll
    for (int j = 0; j < 4; j++) {
      int col = n0 + j * 16 + l15;
      float bv = bias[col];
#pragma unroll
      for (int r = 0; r < 4; r++) {
        int row = m0 + w * 32 + i * 16 + quad * 4 + r;
        Cout[(size_t)row * N + col] = acc[i][j][r] + bv;
      }
    }
  }
}

// ---------------- RMS norm + RoPE -> Q/K head-major bf16 ----------------
__global__ __launch_bounds__(128)
void normrope(const bf16* __restrict__ qkv, const int* __restrict__ idx,
              const float* __restrict__ qnw, const float* __restrict__ knw,
              const float* __restrict__ qnhw, const float* __restrict__ knhw,
              bf16* __restrict__ Qb, bf16* __restrict__ Kb) {
  const int s = blockIdx.x;
  const int y = blockIdx.y;
  const int d = threadIdx.x;

  const bool isq = (y < 16);
  const int off = isq ? (y * HD + d) : (2048 + (y - 16) * HD + d);
  float x = (float)qkv[(size_t)s * QKV_N + off];

  float ss = x * x;
#pragma unroll
  for (int o = 32; o; o >>= 1) ss += __shfl_xor(ss, o);
  float inv = rsqrtf(ss * (1.f / 64.f) + 1e-6f);
  const float* wt = (d < 64) ? (isq ? qnw : knw) : (isq ? qnhw : knhw);
  float yn = x * inv * wt[d & 63];

  float pos, invf;
  int xorm;
  bool firsthalf;
  if (d < 64) {
    pos = (float)idx[s];
    int i = d & 31;
    invf = exp2f(-(float)i * 0.6228615177913804f);  // log2(1e6)/32
    xorm = 32;
    firsthalf = (d < 32);
  } else {
    int j = d - 64;
    int region = j >> 5;
    pos = (float)idx[(1 + region) * S_LEN + s];
    int i = j & 15;
    invf = exp2f(-(float)i * 0.8304820237218406f);  // log2(1e4)/16
    xorm = 16;
    firsthalf = ((j & 31) < 16);
  }
  float ang = pos * invf;
  float si, co;
  sincosf(ang, &si, &co);
  float partner = __shfl_xor(yn, xorm);
  float outv = firsthalf ? (yn * co - partner * si) : (yn * co + partner * si);

  if (isq)
    Qb[((size_t)y * S_LEN + s) * HD + d] = (bf16)outv;
  else
    Kb[((size_t)(y - 16) * S_LEN + s) * HD + d] = (bf16)outv;
}

// ---------------- V transpose: qkvB[s][3072+kv*128+d] -> VT[kv][d][s] ----------------
__global__ __launch_bounds__(256)
void vtrans(const bf16* __restrict__ qkv, bf16* __restrict__ VT) {
  __shared__ bf16 T[64][72];
  const int tid = threadIdx.x;
  const int s0 = blockIdx.x * 64, d0 = blockIdx.y * 64, kv = blockIdx.z;
#pragma unroll
  for (int it = 0; it < 2; it++) {
    int r = (tid >> 3) + it * 32;
    int c = (tid & 7) * 8;
    bf16x8 v = *(const bf16x8*)(qkv + (size_t)(s0 + r) * QKV_N + 3072 + kv * HD + d0 + c);
    *(bf16x8*)(&T[r][c]) = v;
  }
  __syncthreads();
#pragma unroll
  for (int it = 0; it < 2; it++) {
    int r = (tid >> 3) + it * 32;
    int c = (tid & 7) * 8;
    bf16x8 o;
#pragma unroll
    for (int j = 0; j < 8; j++) o[j] = T[c + j][r];
    *(bf16x8*)(VT + ((size_t)kv * HD + d0 + r) * S_LEN + s0 + c) = o;
  }
}

// ---------------- Flash attention: LDS fragment-major staging + pipeline ----------------
// 512 blocks x 256 thr. b: head=b&15, g=b>>4; qb64 = g<16 ? 31-g : g-16 (CU pairs sum const).
// Block owns Q rows qb64*64..+63 (wave w: 16 rows). T-tiles of 64.
// K: double-buffered LDS (16 chunks of 1KB/tile), fragment-major via per-lane gather DMA.
// V: single-buffered (issued first, waited with vmcnt(4) before PV).
__global__ __launch_bounds__(256)
void attn_fused(const bf16* __restrict__ Qb, const bf16* __restrict__ Kb,
                const bf16* __restrict__ VT, bf16* __restrict__ attnO) {
  __shared__ bf16 Kbuf[2][8192];              // 16 KB x2
  __shared__ bf16 Vbuf[8192];                 // 16 KB
  __shared__ __align__(16) bf16 Ps[4][16][72];
  const int tid = threadIdx.x;
  const int w = tid >> 6, lane = tid & 63;
  const int quad = lane >> 4, l15 = lane & 15;
  const int b = blockIdx.x;
  const int h = b & 15;
  const int g = b >> 4;
  const int qb64 = (g < 16) ? (31 - g) : (g - 16);
  const int nT = qb64 + 1;
  const int qr0 = qb64 * 64 + w * 16;
  const int kv = h >> 1;

  const bf16* Qg = Qb + (size_t)h * S_LEN * HD;
  const bf16* Kg = Kb + (size_t)kv * S_LEN * HD;
  const bf16* Vg = VT + (size_t)kv * HD * S_LEN;

  // per-lane DMA source bases (t0 = 0); wave w stages K chunk nt=w, V chunks dt=2w,2w+1
  const bf16* ksrc = Kg + (size_t)(w * 16 + l15) * HD + quad * 8;       // +kc*32, +t0*HD
  const bf16* vsrc = Vg + (size_t)(2 * w * 16 + l15) * S_LEN + quad * 8; // +e*16*S, +t0, +half*32

  // Q fragments (A-layout), resident
  bf16x8 aq[4];
#pragma unroll
  for (int kc = 0; kc < 4; kc++)
    aq[kc] = *(const bf16x8*)(Qg + (size_t)(qr0 + l15) * HD + kc * 32 + quad * 8);

  float m2[4], li[4];
  f32x4 Oacc[8];
#pragma unroll
  for (int r = 0; r < 4; r++) { m2[r] = -1e30f; li[r] = 0.f; }
#pragma unroll
  for (int dt = 0; dt < 8; dt++) Oacc[dt] = (f32x4){0.f, 0.f, 0.f, 0.f};

  const float SC2 = 0.12751745f;  // D^-0.5 * log2(e)

  // prologue: stage K tile 0 into buf 0
#pragma unroll
  for (int kc = 0; kc < 4; kc++)
    async_load16(ksrc + kc * 32, (char*)Kbuf[0] + (w * 4 + kc) * 1024);

  for (int tt = 0; tt < nT; ++tt) {
    const int t0 = tt << 6;
    const int cur = tt & 1;
    const bool more = (tt + 1 < nT);
    __asm__ __volatile__("s_waitcnt vmcnt(0)" ::: "memory");  // own K DMA landed
    __syncthreads();                                          // all waves' DMA landed

    // issue V(tt) first (oldest 4), then K(tt+1) prefetch
#pragma unroll
    for (int e = 0; e < 2; e++)
#pragma unroll
      for (int half = 0; half < 2; half++)
        async_load16(vsrc + (size_t)e * 16 * S_LEN + t0 + half * 32,
                     (char*)Vbuf + (half * 8 + 2 * w + e) * 1024);
    if (more) {
#pragma unroll
      for (int kc = 0; kc < 4; kc++)
        async_load16(ksrc + (size_t)(t0 + 64) * HD + kc * 32,
                     (char*)Kbuf[cur ^ 1] + (w * 4 + kc) * 1024);
    }

    // ---- QK^T from Kbuf[cur] (conflict-free lane-linear reads) ----
    f32x4 sacc[4];
#pragma unroll
    for (int nt = 0; nt < 4; nt++) {
      sacc[nt] = (f32x4){0.f, 0.f, 0.f, 0.f};
#pragma unroll
      for (int kc = 0; kc < 4; kc++) {
        bf16x8 bk = *(const bf16x8*)((const char*)Kbuf[cur] + (nt * 4 + kc) * 1024 + lane * 16);
        sacc[nt] = __builtin_amdgcn_mfma_f32_16x16x32_bf16(aq[kc], bk, sacc[nt], 0, 0, 0);
      }
    }

    // ---- online softmax (base-2, DPP reductions over l15) ----
    const bool full = (t0 + 64 <= qr0);
#pragma unroll
    for (int r = 0; r < 4; r++) {
      const int mrow = qr0 + quad * 4 + r;
      float s0 = sacc[0][r] * SC2, s1 = sacc[1][r] * SC2;
      float s2 = sacc[2][r] * SC2, s3 = sacc[3][r] * SC2;
      if (!full) {
        int cb = t0 + l15;
        if (cb > mrow) s0 = -1e30f;
        if (cb + 16 > mrow) s1 = -1e30f;
        if (cb + 32 > mrow) s2 = -1e30f;
        if (cb + 48 > mrow) s3 = -1e30f;
      }
      float mx = rowmax16(fmaxf(fmaxf(s0, s1), fmaxf(s2, s3)));
      float mnew = fmaxf(m2[r], mx);
      float alpha = exp2f(m2[r] - mnew);
      float p0 = exp2f(s0 - mnew), p1 = exp2f(s1 - mnew);
      float p2 = exp2f(s2 - mnew), p3 = exp2f(s3 - mnew);
      float rs = rowsum16((p0 + p1) + (p2 + p3));
      li[r] = li[r] * alpha + rs;
      m2[r] = mnew;
#pragma unroll
      for (int dt = 0; dt < 8; dt++) Oacc[dt][r] *= alpha;
      Ps[w][quad * 4 + r][l15] = (bf16)p0;
      Ps[w][quad * 4 + r][16 + l15] = (bf16)p1;
      Ps[w][quad * 4 + r][32 + l15] = (bf16)p2;
      Ps[w][quad * 4 + r][48 + l15] = (bf16)p3;
    }
    __asm__ __volatile__("s_waitcnt lgkmcnt(0)" ::: "memory");  // P RAW (wave-local)
    if (more)
      __asm__ __volatile__("s_waitcnt vmcnt(4)" ::: "memory");  // V landed (K prefetch stays)
    else
      __asm__ __volatile__("s_waitcnt vmcnt(0)" ::: "memory");

    // ---- PV from Vbuf (conflict-free lane-linear reads) ----
#pragma unroll
    for (int half = 0; half < 2; half++) {
      bf16x8 ap = *(const bf16x8*)(&Ps[w][l15][half * 32 + quad * 8]);
#pragma unroll
      for (int dt = 0; dt < 8; dt++) {
        bf16x8 bv = *(const bf16x8*)((const char*)Vbuf + (half * 8 + dt) * 1024 + lane * 16);
        Oacc[dt] = __builtin_amdgcn_mfma_f32_16x16x32_bf16(ap, bv, Oacc[dt], 0, 0, 0);
      }
    }
  }

#pragma unroll
  for (int r = 0; r < 4; r++) {
    float invl = 1.f / li[r];
    int srow = qr0 + quad * 4 + r;
#pragma unroll
    for (int dt = 0; dt < 8; dt++)
      attnO[(size_t)srow * HIDDEN + h * HD + dt * 16 + l15] = (bf16)(Oacc[dt][r] * invl);
  }
}

extern "C" void kernel_launch(void* const* d_in, const int* in_sizes, int n_in,
                              void* d_out, int out_size, void* d_ws, size_t ws_size,
                              hipStream_t stream) {
  const float* hidden = (const float*)d_in[0];
  const int* idx = (const int*)d_in[1];
  const float* qkv_w = (const float*)d_in[3];
  const float* qkv_b = (const float*)d_in[4];
  const float* o_w = (const float*)d_in[5];
  const float* o_b = (const float*)d_in[6];
  const float* qnw = (const float*)d_in[7];
  const float* knw = (const float*)d_in[8];
  const float* qnhw = (const float*)d_in[9];
  const float* knhw = (const float*)d_in[10];

  char* ws = (char*)d_ws;
  bf16* hB   = (bf16*)(ws);               // 8 MB
  bf16* qwB  = (bf16*)(ws + (8u << 20));  // 16 MB
  bf16* qkvB = (bf16*)(ws + (24u << 20)); // 16 MB
  bf16* Qb   = (bf16*)(ws + (40u << 20)); // 8 MB
  bf16* Kb   = (bf16*)(ws + (48u << 20)); // 4 MB
  bf16* VT   = (bf16*)(ws + (52u << 20)); // 4 MB
  bf16* owB  = hB;                        // reuse after GEMM1
  bf16* attn = qwB;                       // reuse after GEMM1

  cvt_f32_bf16<<<HIDDEN * S_LEN / 1024, 256, 0, stream>>>(hidden, hB, HIDDEN * S_LEN);
  cvt_f32_bf16<<<QKV_N * HIDDEN / 1024, 256, 0, stream>>>(qkv_w, qwB, QKV_N * HIDDEN);

  gemm_bt<1><<<dim3(QKV_N / 128, S_LEN / 128), 256, 0, stream>>>(
      hB, qwB, qkv_b, qkvB, S_LEN, QKV_N, HIDDEN);

  cvt_f32_bf16<<<HIDDEN * HIDDEN / 1024, 256, 0, stream>>>(o_w, owB, HIDDEN * HIDDEN);

  normrope<<<dim3(S_LEN, 24), 128, 0, stream>>>(qkvB, idx, qnw, knw, qnhw, knhw, Qb, Kb);
  vtrans<<<dim3(S_LEN / 64, HD / 64, NKV), 256, 0, stream>>>(qkvB, VT);

  attn_fused<<<512, 256, 0, stream>>>(Qb, Kb, VT, attn);

  gemm_bt64<<<dim3(HIDDEN / 64, S_LEN / 128), 256, 0, stream>>>(
      attn, owB, o_b, (float*)d_out, S_LEN, HIDDEN, HIDDEN);
}